// Round 3
// baseline (32669.522 us; speedup 1.0000x reference)
//
#include <hip/hip_runtime.h>
#include <hip/hip_bf16.h>

// Problem constants (match reference)
#define DIMN 100
#define NPATH 8192
#define NT 50
#define HW 256
#define RRATE 0.05f

typedef __hip_bfloat16 bf16;

// dtype-flag-branched input loader: f32 != 0 -> fp32 array, else bf16 array
__device__ __forceinline__ float ldin(const void* p, long i, int f32) {
    return f32 ? ((const float*)p)[i] : __bfloat162float(((const bf16*)p)[i]);
}

// ---------------- probe input dtype + zero err accumulator ----------------
// timegrid = linspace(0,1,50). fp32: bytes 2..3 (high half of 0.0f) == 0.
// bf16: element 1 = bf16(1/49) = 0x3CA7 != 0.
__global__ void probe_kernel(const void* tgp, int* flag, float* err) {
    const int i = blockIdx.x * blockDim.x + threadIdx.x;
    if (i == 0) {
        const unsigned short* u = (const unsigned short*)tgp;
        *flag = (u[1] == 0) ? 1 : 0;
    }
    if (i < NPATH) err[i] = 0.f;
}

// ---------------- init: S_carry (f32) from S0; Vt[k][d] = V[d][k] (f32) ----------
__global__ void init_kernel(const void* S0, float* S_carry,
                            const void* V, float* Vt, const int* dflag) {
    const int f = *dflag;
    const long i = (long)blockIdx.x * blockDim.x + threadIdx.x;
    if (i < (long)NPATH * DIMN) S_carry[i] = ldin(S0, i, f);
    if (i < DIMN * DIMN) {
        const long d = i / DIMN, k = i % DIMN;
        Vt[k * DIMN + d] = ldin(V, d * DIMN + k, f);
    }
}

// ---------------- GEMM: C[M,N] = act(A[M,K] @ B[K,N] + bias + t*w0) ----------------
// A_RAW: A is a raw input (dtype per flag), scalar guarded loads.
// !A_RAW: A is f32 workspace, float4 loads (16B-aligned; tail overrun <=12B must
//         stay inside the workspace -- guaranteed by carve order).
// B_RAW: B is raw input (dtype per flag); else f32 workspace. bias/w0/tg are raw.
// Tile 128x128, 8x8 per thread. M multiple of 128.
template <bool A_RAW, bool B_RAW, bool RELU>
__global__ __launch_bounds__(256)
void gemm_kernel(const void* A, long aOff, int K,
                 const void* Bw, long bOff, int N,
                 const void* bias, long biasOff,
                 const void* w0, const void* tgp, int t,
                 float* __restrict__ Cout, const int* dflag)
{
    const int f = *dflag;
    __shared__ float As[8][128];
    __shared__ float Bs[8][128];
    const int tid = threadIdx.x;
    const int tx = tid & 15, ty = tid >> 4;
    const long rowBase = (long)blockIdx.x * 128;
    const int colBase = blockIdx.y * 128;

    float acc[8][8];
#pragma unroll
    for (int i = 0; i < 8; i++)
#pragma unroll
        for (int j = 0; j < 8; j++) acc[i][j] = 0.f;

    for (int k0 = 0; k0 < K; k0 += 8) {
        // ---- stage A tile (128 rows x 8 k), transposed into As[k][row] ----
        {
            const int l = tid * 4;
            const int row = l >> 3;
            const int col = l & 7;   // 0 or 4
            const long abase = aOff + (rowBase + row) * (long)K + (k0 + col);
            if (A_RAW) {
#pragma unroll
                for (int q = 0; q < 4; q++)
                    As[col + q][row] = (k0 + col + q < K) ? ldin(A, abase + q, f) : 0.f;
            } else {
                const float4 av = *(const float4*)((const float*)A + abase);
                const float avv[4] = {av.x, av.y, av.z, av.w};
#pragma unroll
                for (int q = 0; q < 4; q++)
                    As[col + q][row] = (k0 + col + q < K) ? avv[q] : 0.f;
            }
        }
        // ---- stage B tile (8 k x 128 cols) into Bs[k][col] ----
#pragma unroll
        for (int q = 0; q < 4; q++) {
            const int l = tid + 256 * q;
            const int kk = l >> 7, col = l & 127;
            const int gk = k0 + kk, gc = colBase + col;
            float bv = 0.f;
            if (gk < K && gc < N) {
                const long bi = bOff + (long)gk * N + gc;
                bv = B_RAW ? ldin(Bw, bi, f) : ((const float*)Bw)[bi];
            }
            Bs[kk][col] = bv;
        }
        __syncthreads();
#pragma unroll
        for (int kk = 0; kk < 8; kk++) {
            float a[8], b[8];
            const float4 a0 = *(const float4*)&As[kk][ty * 8];
            const float4 a1 = *(const float4*)&As[kk][ty * 8 + 4];
            const float4 b0 = *(const float4*)&Bs[kk][tx * 8];
            const float4 b1 = *(const float4*)&Bs[kk][tx * 8 + 4];
            a[0]=a0.x;a[1]=a0.y;a[2]=a0.z;a[3]=a0.w;a[4]=a1.x;a[5]=a1.y;a[6]=a1.z;a[7]=a1.w;
            b[0]=b0.x;b[1]=b0.y;b[2]=b0.z;b[3]=b0.w;b[4]=b1.x;b[5]=b1.y;b[6]=b1.z;b[7]=b1.w;
#pragma unroll
            for (int i = 0; i < 8; i++)
#pragma unroll
                for (int j = 0; j < 8; j++)
                    acc[i][j] += a[i] * b[j];
        }
        __syncthreads();
    }

    // ---- epilogue: bias + t*w0, optional ReLU ----
    const float tval = w0 ? ldin(tgp, t, f) : 0.f;
    float add[8];
#pragma unroll
    for (int j = 0; j < 8; j++) {
        const int col = colBase + tx * 8 + j;
        float a = 0.f;
        if (col < N) {
            if (bias) a += ldin(bias, biasOff + col, f);
            if (w0)   a += tval * ldin(w0, (long)col, f);
        }
        add[j] = a;
    }
#pragma unroll
    for (int i = 0; i < 8; i++) {
        const long row = rowBase + ty * 8 + i;
        const int colb = colBase + tx * 8;
        float v[8];
#pragma unroll
        for (int j = 0; j < 8; j++) {
            float x = acc[i][j] + add[j];
            if (RELU) x = fmaxf(x, 0.f);
            v[j] = x;
        }
        if (colb + 7 < N) {
            float4* cp = (float4*)(Cout + row * (long)N + colb);
            cp[0] = make_float4(v[0], v[1], v[2], v[3]);
            cp[1] = make_float4(v[4], v[5], v[6], v[7]);
        } else {
#pragma unroll
            for (int j = 0; j < 8; j++)
                if (colb + j < N) Cout[row * (long)N + colb + j] = v[j];
        }
    }
}

// ---------------- stoch_int: one wave per row; sum_d grad*S*D*sqrt(h) ----------------
__global__ __launch_bounds__(256)
void stoch_kernel(const float* __restrict__ grad, const float* __restrict__ S,
                  const float* __restrict__ D, const void* tgp, int t,
                  float* __restrict__ st_out, int R, const int* dflag)
{
    const int f = *dflag;
    const int wid = threadIdx.x >> 6, lane = threadIdx.x & 63;
    const long row = (long)blockIdx.x * 4 + wid;
    if (row >= R) return;
    const long base = row * DIMN;
    float s = 0.f;
    if (lane < DIMN) s += grad[base + lane] * S[base + lane] * D[base + lane];
    const int d2 = lane + 64;
    if (d2 < DIMN) s += grad[base + d2] * S[base + d2] * D[base + d2];
    for (int off = 32; off; off >>= 1) s += __shfl_down(s, off);
    if (lane == 0) {
        const float h = ldin(tgp, t + 1, f) - ldin(tgp, t, f);
        st_out[row] = sqrtf(h) * s;
    }
}

// ---------------- v output layer (N=1) + error fold ----------------
// v = H @ wv + bv; err += (v - v_prev*(1+r*h_{t-1}) - stoch_prev)^2 when fold!=0
__global__ __launch_bounds__(256)
void vout_kernel(const float* __restrict__ H, const void* wv, const void* bv,
                 float* __restrict__ v_cur, const float* __restrict__ v_prev,
                 const float* __restrict__ st_prev, float* __restrict__ err,
                 const void* tgp, int t, int fold, int R, const int* dflag)
{
    const int f = *dflag;
    const int wid = threadIdx.x >> 6, lane = threadIdx.x & 63;
    const long row = (long)blockIdx.x * 4 + wid;
    if (row >= R) return;
    const float4 h4 = *(const float4*)(H + row * (long)HW + lane * 4);
    float s = h4.x * ldin(wv, lane * 4 + 0, f) + h4.y * ldin(wv, lane * 4 + 1, f) +
              h4.z * ldin(wv, lane * 4 + 2, f) + h4.w * ldin(wv, lane * 4 + 3, f);
    for (int off = 32; off; off >>= 1) s += __shfl_down(s, off);
    if (lane == 0) {
        const float v = s + ldin(bv, 0, f);
        v_cur[row] = v;
        if (fold) {
            const float h = ldin(tgp, t, f) - ldin(tgp, t - 1, f);
            const float e = v - v_prev[row] * (1.f + RRATE * h) - st_prev[row];
            err[row] += e * e;
        }
    }
}

// ---------------- S update: s += r*s*h + s*D*sqrt(h); optional S_f emit ----------------
__global__ __launch_bounds__(256)
void update_kernel(float* __restrict__ S, const float* __restrict__ D,
                   const void* tgp, int t, int n,
                   void* outBase, long oOff, int writeSf, const int* dflag)
{
    const int f = *dflag;
    const long i = (long)blockIdx.x * blockDim.x + threadIdx.x;
    if (i >= n) return;
    float s = S[i];
    const float h = ldin(tgp, t + 1, f) - ldin(tgp, t, f);
    s = s + RRATE * s * h + s * D[i] * sqrtf(h);
    S[i] = s;
    if (writeSf) {
        if (f) ((float*)outBase)[oOff + i] = s;
        else   ((bf16*)outBase)[oOff + i] = __float2bfloat16(s);
    }
}

// ---------------- final: v_f and error to out ----------------
__global__ void final_kernel(const float* __restrict__ v_last, const float* __restrict__ err,
                             void* out, const int* dflag)
{
    const int f = *dflag;
    const int b = blockIdx.x * blockDim.x + threadIdx.x;
    if (b >= NPATH) return;
    const long eoff = (long)NPATH + (long)NPATH * DIMN;
    if (f) {
        ((float*)out)[b] = v_last[b];
        ((float*)out)[eoff + b] = err[b];
    } else {
        ((bf16*)out)[b] = __float2bfloat16(v_last[b]);
        ((bf16*)out)[eoff + b] = __float2bfloat16(err[b]);
    }
}

extern "C" void kernel_launch(void* const* d_in, const int* in_sizes, int n_in,
                              void* d_out, int out_size, void* d_ws, size_t ws_size,
                              hipStream_t stream) {
    const void* S0    = d_in[0];
    const void* dW    = d_in[1];
    const void* tg    = d_in[2];
    const void* V     = d_in[3];
    const void* Wg_in = d_in[4];
    const void* bg_in = d_in[5];
    const void* Wg_h  = d_in[6];
    const void* bg_h  = d_in[7];
    const void* Wg_out= d_in[8];
    const void* bg_out= d_in[9];
    const void* Wv_in = d_in[10];
    const void* bv_in = d_in[11];
    const void* Wv_h  = d_in[12];
    const void* bv_h  = d_in[13];
    const void* Wv_out= d_in[14];
    const void* bv_out= d_in[15];

    // ---- carve workspace (minimal fixed part ~3.5 MB) ----
    char* p = (char*)d_ws;
    auto carve = [&](size_t bytes) -> char* {
        char* r = p;
        p += (bytes + 255) & ~(size_t)255;
        return r;
    };
    int*   dflag   = (int*)carve(256);
    float* S_carry = (float*)carve((size_t)NPATH * DIMN * 4);   // 3.28 MB (first: float4 tail-overrun safe)
    float* Vt      = (float*)carve((size_t)DIMN * DIMN * 4);    // 40 KB
    float* err     = (float*)carve((size_t)NPATH * 4);
    float* va      = (float*)carve((size_t)NPATH * 4);
    float* vb      = (float*)carve((size_t)NPATH * 4);
    float* sa      = (float*)carve((size_t)NPATH * 4);
    float* sb      = (float*)carve((size_t)NPATH * 4);
    const size_t fixed = (size_t)(p - (char*)d_ws);

    // path sub-batch PB (multiple of 128): D + grad + H1 + H2 = PB*2848 bytes
    size_t avail = (ws_size > fixed + 4096) ? (ws_size - fixed - 4096) : 0;
    int PB = NPATH;
    while (PB > 128 && (size_t)PB * 2848 > avail) PB >>= 1;
    float* D    = (float*)carve((size_t)PB * DIMN * 4);
    float* grad = (float*)carve((size_t)PB * DIMN * 4);
    float* H1   = (float*)carve((size_t)PB * HW * 4);
    float* H2   = (float*)carve((size_t)PB * HW * 4);

    // ---- prep ----
    probe_kernel<<<dim3(32), dim3(256), 0, stream>>>(tg, dflag, err);
    init_kernel<<<dim3((NPATH * DIMN + 255) / 256), dim3(256), 0, stream>>>(S0, S_carry, V, Vt, dflag);

    float *vp = va, *vc = vb, *sp = sa, *sc = sb;
    const long NB = (long)NPATH * DIMN;

    for (int t = 0; t < NT; t++) {
        const bool last = (t == NT - 1);
        for (int pb0 = 0; pb0 < NPATH; pb0 += PB) {
            const long sOff = (long)pb0 * DIMN;
            const int R = PB;
            dim3 g2(R / 128, 2), g1(R / 128, 1), gw(R / 4), gu((R * DIMN + 255) / 256);

            if (!last) {
                // D = dW[t, pb0:pb0+PB, :] @ V^T   (A raw, B = f32 Vt)
                gemm_kernel<true, false, false><<<g1, 256, 0, stream>>>(
                    dW, (long)t * NB + sOff, DIMN, Vt, 0, DIMN,
                    nullptr, 0, nullptr, tg, t, D, dflag);

                // g-net: [t,S] -> grad
                gemm_kernel<false, true, true><<<g2, 256, 0, stream>>>(
                    S_carry, sOff, DIMN, Wg_in, HW, HW, bg_in, 0, Wg_in, tg, t, H1, dflag);
                gemm_kernel<false, true, true><<<g2, 256, 0, stream>>>(
                    H1, 0, HW, Wg_h, 0, HW, bg_h, 0, nullptr, tg, t, H2, dflag);
                gemm_kernel<false, true, true><<<g2, 256, 0, stream>>>(
                    H2, 0, HW, Wg_h, (long)HW * HW, HW, bg_h, HW, nullptr, tg, t, H1, dflag);
                gemm_kernel<false, true, true><<<g2, 256, 0, stream>>>(
                    H1, 0, HW, Wg_h, 2L * HW * HW, HW, bg_h, 2 * HW, nullptr, tg, t, H2, dflag);
                gemm_kernel<false, true, false><<<g1, 256, 0, stream>>>(
                    H2, 0, HW, Wg_out, 0, DIMN, bg_out, 0, nullptr, tg, t, grad, dflag);
                stoch_kernel<<<gw, 256, 0, stream>>>(grad, S_carry + sOff, D, tg, t,
                                                     sc + pb0, R, dflag);
            }

            // v-net: [t,S] -> v
            gemm_kernel<false, true, true><<<g2, 256, 0, stream>>>(
                S_carry, sOff, DIMN, Wv_in, HW, HW, bv_in, 0, Wv_in, tg, t, H1, dflag);
            gemm_kernel<false, true, true><<<g2, 256, 0, stream>>>(
                H1, 0, HW, Wv_h, 0, HW, bv_h, 0, nullptr, tg, t, H2, dflag);
            gemm_kernel<false, true, true><<<g2, 256, 0, stream>>>(
                H2, 0, HW, Wv_h, (long)HW * HW, HW, bv_h, HW, nullptr, tg, t, H1, dflag);
            gemm_kernel<false, true, true><<<g2, 256, 0, stream>>>(
                H1, 0, HW, Wv_h, 2L * HW * HW, HW, bv_h, 2 * HW, nullptr, tg, t, H2, dflag);
            vout_kernel<<<gw, 256, 0, stream>>>(H2, Wv_out, bv_out,
                                                vc + pb0, vp + pb0, sp + pb0, err + pb0,
                                                tg, t, t > 0 ? 1 : 0, R, dflag);

            if (!last) {
                // advance S for this path block; emit S_f (out elements NPATH..NPATH+B*DIM) at t=48
                update_kernel<<<gu, 256, 0, stream>>>(S_carry + sOff, D, tg, t, R * DIMN,
                                                      d_out, (long)NPATH + sOff,
                                                      (t == NT - 2) ? 1 : 0, dflag);
            }
        }
        // ping-pong cur <-> prev (deterministic per launch)
        float* tmp;
        tmp = vp; vp = vc; vc = tmp;
        tmp = sp; sp = sc; sc = tmp;
    }

    // after final swap, vp = v at t=49
    final_kernel<<<dim3(NPATH / 256), dim3(256), 0, stream>>>(vp, err, d_out, dflag);
}

// Round 4
// 8187.482 us; speedup vs baseline: 3.9902x; 3.9902x over previous
//
#include <hip/hip_runtime.h>
#include <hip/hip_bf16.h>
#include <type_traits>

// Problem constants (match reference)
#define DIMN 100
#define NPATH 8192
#define NT 50
#define HW 256
#define RRATE 0.05f

typedef __hip_bfloat16 bf16;

// dtype-flag-branched input loader: f32 != 0 -> fp32 array, else bf16 array
__device__ __forceinline__ float ldin(const void* p, long i, int f32) {
    return f32 ? ((const float*)p)[i] : __bfloat162float(((const bf16*)p)[i]);
}

// ---------------- probe input dtype ----------------
// timegrid = linspace(0,1,50). fp32: u16[1] (high half of 0.0f) == 0.
// bf16: element 1 = bf16(1/49) = 0x3CA7 != 0.
__global__ void probe_kernel(const void* tgp, int* flag) {
    if (threadIdx.x == 0 && blockIdx.x == 0) {
        const unsigned short* u = (const unsigned short*)tgp;
        *flag = (u[1] == 0) ? 1 : 0;
    }
}

// ---------------- init: S_carry (f32) from S0; Vt[k][d] = V[d][k] (f32) ----------
__global__ void init_kernel(const void* S0, float* S_carry,
                            const void* V, float* Vt, const int* dflag) {
    const int f = *dflag;
    const long i = (long)blockIdx.x * blockDim.x + threadIdx.x;
    if (i < (long)NPATH * DIMN) S_carry[i] = ldin(S0, i, f);
    if (i < DIMN * DIMN) {
        const long d = i / DIMN, k = i % DIMN;
        Vt[k * DIMN + d] = ldin(V, d * DIMN + k, f);
    }
}

// ---------------- GEMM used only for D = dW @ V^T (A raw, B f32) ----------------
// Proven round-2 kernel. Tile 128x128, 8x8/thread. M multiple of 128.
template <bool A_RAW, bool B_RAW, bool RELU>
__global__ __launch_bounds__(256)
void gemm_kernel(const void* A, long aOff, int K,
                 const void* Bw, long bOff, int N,
                 const void* bias, long biasOff,
                 const void* w0, const void* tgp, int t,
                 float* __restrict__ Cout, const int* dflag)
{
    const int f = *dflag;
    __shared__ float As[8][128];
    __shared__ float Bs[8][128];
    const int tid = threadIdx.x;
    const int tx = tid & 15, ty = tid >> 4;
    const long rowBase = (long)blockIdx.x * 128;
    const int colBase = blockIdx.y * 128;

    float acc[8][8];
#pragma unroll
    for (int i = 0; i < 8; i++)
#pragma unroll
        for (int j = 0; j < 8; j++) acc[i][j] = 0.f;

    for (int k0 = 0; k0 < K; k0 += 8) {
        {
            const int l = tid * 4;
            const int row = l >> 3;
            const int col = l & 7;   // 0 or 4
            const long abase = aOff + (rowBase + row) * (long)K + (k0 + col);
            if (A_RAW) {
#pragma unroll
                for (int q = 0; q < 4; q++)
                    As[col + q][row] = (k0 + col + q < K) ? ldin(A, abase + q, f) : 0.f;
            } else {
                const float4 av = *(const float4*)((const float*)A + abase);
                const float avv[4] = {av.x, av.y, av.z, av.w};
#pragma unroll
                for (int q = 0; q < 4; q++)
                    As[col + q][row] = (k0 + col + q < K) ? avv[q] : 0.f;
            }
        }
#pragma unroll
        for (int q = 0; q < 4; q++) {
            const int l = tid + 256 * q;
            const int kk = l >> 7, col = l & 127;
            const int gk = k0 + kk, gc = colBase + col;
            float bv = 0.f;
            if (gk < K && gc < N) {
                const long bi = bOff + (long)gk * N + gc;
                bv = B_RAW ? ldin(Bw, bi, f) : ((const float*)Bw)[bi];
            }
            Bs[kk][col] = bv;
        }
        __syncthreads();
#pragma unroll
        for (int kk = 0; kk < 8; kk++) {
            float a[8], b[8];
            const float4 a0 = *(const float4*)&As[kk][ty * 8];
            const float4 a1 = *(const float4*)&As[kk][ty * 8 + 4];
            const float4 b0 = *(const float4*)&Bs[kk][tx * 8];
            const float4 b1 = *(const float4*)&Bs[kk][tx * 8 + 4];
            a[0]=a0.x;a[1]=a0.y;a[2]=a0.z;a[3]=a0.w;a[4]=a1.x;a[5]=a1.y;a[6]=a1.z;a[7]=a1.w;
            b[0]=b0.x;b[1]=b0.y;b[2]=b0.z;b[3]=b0.w;b[4]=b1.x;b[5]=b1.y;b[6]=b1.z;b[7]=b1.w;
#pragma unroll
            for (int i = 0; i < 8; i++)
#pragma unroll
                for (int j = 0; j < 8; j++)
                    acc[i][j] += a[i] * b[j];
        }
        __syncthreads();
    }

    const float tval = w0 ? ldin(tgp, t, f) : 0.f;
    float add[8];
#pragma unroll
    for (int j = 0; j < 8; j++) {
        const int col = colBase + tx * 8 + j;
        float a = 0.f;
        if (col < N) {
            if (bias) a += ldin(bias, biasOff + col, f);
            if (w0)   a += tval * ldin(w0, (long)col, f);
        }
        add[j] = a;
    }
#pragma unroll
    for (int i = 0; i < 8; i++) {
        const long row = rowBase + ty * 8 + i;
        const int colb = colBase + tx * 8;
        float v[8];
#pragma unroll
        for (int j = 0; j < 8; j++) {
            float x = acc[i][j] + add[j];
            if (RELU) x = fmaxf(x, 0.f);
            v[j] = x;
        }
        if (colb + 7 < N) {
            float4* cp = (float4*)(Cout + row * (long)N + colb);
            cp[0] = make_float4(v[0], v[1], v[2], v[3]);
            cp[1] = make_float4(v[4], v[5], v[6], v[7]);
        } else {
#pragma unroll
            for (int j = 0; j < 8; j++)
                if (colb + j < N) Cout[row * (long)N + colb + j] = v[j];
        }
    }
}

// ---------------- chunked S scan over Cg timesteps ----------------
// Per (b,d): S_chunk[lt]=s (S at t0+lt), then s = s*(1+r*h) + s*D*sqrt(h).
__global__ __launch_bounds__(256)
void scan_chunk_kernel(float* __restrict__ S_carry, const float* __restrict__ D_chunk,
                       const void* tgp, float* __restrict__ S_chunk,
                       int t0, int Cg, void* outBase, int writeSf,
                       const int* __restrict__ dflag)
{
    const int f = *dflag;
    const long idx = (long)blockIdx.x * blockDim.x + threadIdx.x;
    if (idx >= (long)NPATH * DIMN) return;
    float s = S_carry[idx];
    for (int lt = 0; lt < Cg; lt++) {
        const int t = t0 + lt;
        const float h = ldin(tgp, t + 1, f) - ldin(tgp, t, f);
        const long off = (long)lt * (NPATH * DIMN) + idx;
        S_chunk[off] = s;
        s = s + RRATE * s * h + s * D_chunk[off] * sqrtf(h);
    }
    S_carry[idx] = s;
    if (writeSf) {
        if (f) ((float*)outBase)[NPATH + idx] = s;
        else   ((bf16*)outBase)[NPATH + idx] = __float2bfloat16(s);
    }
}

// ---------------- fused 5-layer MLP (64 rows/block, activations in LDS) ----------
// GNET: out = stoch_int rows; VNET: out = v rows. Ssrc rows = Cg*8192 (row=lt*8192+b).
// LDS: Hs[k][row] k-major (stride 68 -> 16B-aligned b128 broadcast reads);
// Ws 8xN weight tile (stride 260). Microtile: 8 rows x (4x2) cols, cols=64g+2tx+c
// -> B-reads are ds_read_b64 at 2-way bank conflict (free, m136).
template <bool GNET>
__global__ __launch_bounds__(256)
void mlp_kernel(const float* __restrict__ Ssrc, const float* __restrict__ Dsrc,
                const void* W_in, const void* b_in,
                const void* W_h, const void* b_h,
                const void* W_out, const void* b_out,
                const void* tgp, int t0,
                float* __restrict__ outv, const int* __restrict__ dflag)
{
    const int f = *dflag;
    __shared__ __align__(16) float Hs[256][68];
    __shared__ __align__(16) float Ws[8][260];
    const int tid = threadIdx.x;
    const int tx = tid & 31, ty = tid >> 5;
    const long row0 = (long)blockIdx.x * 64;
    const int t = t0 + (int)(row0 >> 13);   // 64 | 8192: all rows of a block share t

    // ---- stage input x = [t, S] into Hs[k][r]; zero-pad k=101..103 ----
    {
        const int r = tid >> 2, part = tid & 3;
        if (part == 0) Hs[0][r] = ldin(tgp, t, f);
        const long sbase = (row0 + r) * DIMN;
        const int c0 = part * 25;
        for (int m = 0; m < 25; m++)
            Hs[1 + c0 + m][r] = Ssrc[sbase + c0 + m];
        if (tid < 64) { Hs[101][tid] = 0.f; Hs[102][tid] = 0.f; Hs[103][tid] = 0.f; }
    }
    __syncthreads();

    const int NL = GNET ? 5 : 4;
    float acc[8][8];
    for (int l = 0; l < NL; l++) {
        const int K = (l == 0) ? 101 : HW;
        const int N = (l == 4) ? DIMN : HW;   // l==4 only for GNET
        const void* Wp; long wOff;
        if (l == 0)      { Wp = W_in;  wOff = 0; }
        else if (l < 4)  { Wp = W_h;   wOff = (long)(l - 1) * HW * HW; }
        else             { Wp = W_out; wOff = 0; }

#pragma unroll
        for (int i = 0; i < 8; i++)
#pragma unroll
            for (int j = 0; j < 8; j++) acc[i][j] = 0.f;

        const int nT = (K + 7) >> 3;
        for (int kt = 0; kt < nT; kt++) {
            const int k0 = kt * 8;
            {   // stage Ws[kk][col] (zero outside K x N)
                const int kk = tid >> 5;
                const int c8 = (tid & 31) * 8;
#pragma unroll
                for (int q = 0; q < 8; q++) {
                    const int gk = k0 + kk, gc = c8 + q;
                    Ws[kk][gc] = (gk < K && gc < N) ? ldin(Wp, wOff + (long)gk * N + gc, f) : 0.f;
                }
            }
            __syncthreads();
#pragma unroll
            for (int kk = 0; kk < 8; kk++) {
                const float4 a0 = *(const float4*)&Hs[k0 + kk][ty * 8];
                const float4 a1 = *(const float4*)&Hs[k0 + kk][ty * 8 + 4];
                const float a[8] = {a0.x, a0.y, a0.z, a0.w, a1.x, a1.y, a1.z, a1.w};
                float b[8];
#pragma unroll
                for (int g = 0; g < 4; g++) {
                    const float2 bg = *(const float2*)&Ws[kk][g * 64 + tx * 2];
                    b[g * 2] = bg.x; b[g * 2 + 1] = bg.y;
                }
#pragma unroll
                for (int i = 0; i < 8; i++)
#pragma unroll
                    for (int j = 0; j < 8; j++)
                        acc[i][j] += a[i] * b[j];
            }
            __syncthreads();
        }

        if (l < 4) {   // bias + relu + write back to Hs
            const void* bp = (l == 0) ? b_in : b_h;
            const long bOff2 = (l == 0) ? 0 : (long)(l - 1) * HW;
#pragma unroll
            for (int g = 0; g < 4; g++)
#pragma unroll
            for (int c = 0; c < 2; c++) {
                const int col = g * 64 + tx * 2 + c;
                const float bb = ldin(bp, bOff2 + col, f);
#pragma unroll
                for (int i = 0; i < 8; i++)
                    Hs[col][ty * 8 + i] = fmaxf(acc[i][g * 2 + c] + bb, 0.f);
            }
            __syncthreads();
        }
    }

    if (GNET) {
        // stoch = sqrt(h) * sum_col grad[r][col] * S[r][col] * D[r][col]
        const float h = ldin(tgp, t + 1, f) - ldin(tgp, t, f);
        const float sq = sqrtf(h);
        float sp[8];
#pragma unroll
        for (int i = 0; i < 8; i++) sp[i] = 0.f;
#pragma unroll
        for (int g = 0; g < 4; g++)
#pragma unroll
        for (int c = 0; c < 2; c++) {
            const int col = g * 64 + tx * 2 + c;
            if (col < DIMN) {
                const float bo = ldin(b_out, col, f);
#pragma unroll
                for (int i = 0; i < 8; i++) {
                    const long rr = row0 + ty * 8 + i;
                    const float sv = Ssrc[rr * DIMN + col] * Dsrc[rr * DIMN + col];
                    sp[i] += (acc[i][g * 2 + c] + bo) * sv;
                }
            }
        }
#pragma unroll
        for (int i = 0; i < 8; i++)
            for (int off = 16; off; off >>= 1)
                sp[i] += __shfl_down(sp[i], off, 32);
        if (tx == 0) {
#pragma unroll
            for (int i = 0; i < 8; i++)
                outv[row0 + ty * 8 + i] = sp[i] * sq;
        }
    } else {
        // v = H4 . W_out + b_out  (N=1): 4 threads per row, 64 k each
        const int r = tid >> 2, part = tid & 3;
        float s = 0.f;
        for (int m = 0; m < 64; m++) {
            const int k = part * 64 + m;
            s += Hs[k][r] * ldin(W_out, k, f);
        }
        s += __shfl_down(s, 2, 4);
        s += __shfl_down(s, 1, 4);
        if (part == 0) outv[row0 + r] = s + ldin(b_out, 0, f);
    }
}

// ---------------- final: error accumulation + v_f ----------------
__global__ void final_kernel(const float* __restrict__ v_all, const float* __restrict__ stoch,
                             const void* tgp, void* out, const int* __restrict__ dflag)
{
    const int f = *dflag;
    const int b = blockIdx.x * blockDim.x + threadIdx.x;
    if (b >= NPATH) return;
    float err = 0.f;
    for (int i = 0; i < NT - 1; i++) {
        const float h = ldin(tgp, i + 1, f) - ldin(tgp, i, f);
        const float e = v_all[(i + 1) * NPATH + b] - v_all[i * NPATH + b] * (1.f + RRATE * h)
                        - stoch[i * NPATH + b];
        err += e * e;
    }
    const long eoff = (long)NPATH + (long)NPATH * DIMN;
    const float vf = v_all[(long)(NT - 1) * NPATH + b];
    if (f) {
        ((float*)out)[b] = vf;
        ((float*)out)[eoff + b] = err;
    } else {
        ((bf16*)out)[b] = __float2bfloat16(vf);
        ((bf16*)out)[eoff + b] = __float2bfloat16(err);
    }
}

static inline int imin(int a, int b) { return a < b ? a : b; }

extern "C" void kernel_launch(void* const* d_in, const int* in_sizes, int n_in,
                              void* d_out, int out_size, void* d_ws, size_t ws_size,
                              hipStream_t stream) {
    const void* S0    = d_in[0];
    const void* dW    = d_in[1];
    const void* tg    = d_in[2];
    const void* V     = d_in[3];
    const void* Wg_in = d_in[4];
    const void* bg_in = d_in[5];
    const void* Wg_h  = d_in[6];
    const void* bg_h  = d_in[7];
    const void* Wg_out= d_in[8];
    const void* bg_out= d_in[9];
    const void* Wv_in = d_in[10];
    const void* bv_in = d_in[11];
    const void* Wv_h  = d_in[12];
    const void* bv_h  = d_in[13];
    const void* Wv_out= d_in[14];
    const void* bv_out= d_in[15];

    const size_t SZ_SD = (size_t)NPATH * DIMN * 4;   // 3,276,800 B per timestep

    // ---- carve workspace ----
    char* p = (char*)d_ws;
    auto carve = [&](size_t bytes) -> char* {
        char* r = p;
        p += (bytes + 255) & ~(size_t)255;
        return r;
    };
    int*   dflag     = (int*)carve(256);
    float* S_carry   = (float*)carve(SZ_SD);                          // 3.28 MB
    float* Vt        = (float*)carve((size_t)DIMN * DIMN * 4);        // 40 KB
    float* v_all     = (float*)carve((size_t)NT * NPATH * 4);         // 1.64 MB
    float* stoch_all = (float*)carve((size_t)(NT - 1) * NPATH * 4);   // 1.61 MB
    const size_t fixed = (size_t)(p - (char*)d_ws);

    // adaptive time-chunk: per-timestep cost = S_chunk + D_chunk (6.55 MB)
    const size_t perC = 2 * SZ_SD;
    size_t avail = (ws_size > fixed + 65536) ? (ws_size - fixed - 65536) : 0;
    int C = (int)(avail / perC);
    if (C < 1) C = 1;                                                  // floor ~13.2 MB
    if (C > NT - 1) C = NT - 1;
    float* S_chunk = (float*)carve((size_t)C * SZ_SD);
    float* D_chunk = (float*)carve((size_t)C * SZ_SD);

    // ---- prep ----
    probe_kernel<<<dim3(1), dim3(64), 0, stream>>>(tg, dflag);
    init_kernel<<<dim3((NPATH * DIMN + 255) / 256), dim3(256), 0, stream>>>(S0, S_carry, V, Vt, dflag);

    // ---- chunk loop over timesteps t in [0, 49) ----
    for (int t0 = 0; t0 < NT - 1; t0 += C) {
        const int Cg = imin(C, NT - 1 - t0);
        const int rows = Cg * NPATH;

        // D_chunk = dW[t0..t0+Cg) @ V^T   (K=N=100)
        gemm_kernel<true, false, false><<<dim3(rows / 128, 1), 256, 0, stream>>>(
            dW, (long)t0 * NPATH * DIMN, DIMN, Vt, 0, DIMN,
            nullptr, 0, nullptr, tg, 0, D_chunk, dflag);

        // scan: emit S_chunk (S at each t), advance S_carry; S_f on last chunk
        scan_chunk_kernel<<<dim3((NPATH * DIMN + 255) / 256), 256, 0, stream>>>(
            S_carry, D_chunk, tg, S_chunk, t0, Cg, d_out,
            (t0 + Cg == NT - 1) ? 1 : 0, dflag);

        // g-net (fused 5 layers + stoch epilogue)
        mlp_kernel<true><<<dim3(rows / 64), 256, 0, stream>>>(
            S_chunk, D_chunk, Wg_in, bg_in, Wg_h, bg_h, Wg_out, bg_out,
            tg, t0, stoch_all + (long)t0 * NPATH, dflag);

        // v-net (fused 4 layers + output-dot epilogue)
        mlp_kernel<false><<<dim3(rows / 64), 256, 0, stream>>>(
            S_chunk, nullptr, Wv_in, bv_in, Wv_h, bv_h, Wv_out, bv_out,
            tg, t0, v_all + (long)t0 * NPATH, dflag);
    }

    // ---- v at t = 49 from S_carry ----
    mlp_kernel<false><<<dim3(NPATH / 64), 256, 0, stream>>>(
        S_carry, nullptr, Wv_in, bv_in, Wv_h, bv_h, Wv_out, bv_out,
        tg, NT - 1, v_all + (long)(NT - 1) * NPATH, dflag);

    // ---- error + v_f ----
    final_kernel<<<dim3(NPATH / 256), 256, 0, stream>>>(v_all, stoch_all, tg, d_out, dflag);
}

// Round 5
// 1552.131 us; speedup vs baseline: 21.0482x; 5.2750x over previous
//
#include <hip/hip_runtime.h>
#include <hip/hip_bf16.h>

// Problem constants (match reference)
#define DIMN 100
#define NPATH 8192
#define NT 50
#define HW 256
#define RRATE 0.05f

typedef __hip_bfloat16 bf16;
typedef _Float16 h16;
typedef __attribute__((ext_vector_type(8))) _Float16 h16x8;
typedef __attribute__((ext_vector_type(4))) float f32x4;

// dtype-flag-branched raw-input loader: f32 != 0 -> fp32 array, else bf16 array
__device__ __forceinline__ float ldin(const void* p, long i, int f32) {
    return f32 ? ((const float*)p)[i] : __bfloat162float(((const bf16*)p)[i]);
}

// ---------------- probe input dtype ----------------
__global__ void probe_kernel(const void* tgp, int* flag) {
    if (threadIdx.x == 0 && blockIdx.x == 0) {
        const unsigned short* u = (const unsigned short*)tgp;
        *flag = (u[1] == 0) ? 1 : 0;   // fp32: high half of 0.0f == 0
    }
}

// ---------------- init: S_carry (f32) from S0; Vt[k][d] = V[d][k] (f32) ----------
__global__ void init_kernel(const void* S0, float* S_carry,
                            const void* V, float* Vt, const int* dflag) {
    const int f = *dflag;
    const long i = (long)blockIdx.x * blockDim.x + threadIdx.x;
    if (i < (long)NPATH * DIMN) S_carry[i] = ldin(S0, i, f);
    if (i < DIMN * DIMN) {
        const long d = i / DIMN, k = i % DIMN;
        Vt[k * DIMN + d] = ldin(V, d * DIMN + k, f);
    }
}

// ---------------- pack all MLP weights to fp16 W^T[n][k] layouts ----------------
// Pg0[256][128]  (k<101 from Wg_in[k][n]); Pgh 3x[256][256]; Pgout[128][256] (n<100)
// Pv0[256][128]; Pvh 3x[256][256]. Total 491520 h16.
__global__ void pack_kernel(const void* Wg_in, const void* Wg_h, const void* Wg_out,
                            const void* Wv_in, const void* Wv_h,
                            h16* __restrict__ P, const int* __restrict__ dflag)
{
    const int f = *dflag;
    const long i = (long)blockIdx.x * blockDim.x + threadIdx.x;
    if (i >= 491520) return;
    float v;
    if (i < 32768) {                      // Pg0
        const int n = i >> 7, k = i & 127;
        v = (k < 101) ? ldin(Wg_in, (long)k * 256 + n, f) : 0.f;
    } else if (i < 229376) {              // Pgh
        const long j = i - 32768;
        const int l = (int)(j >> 16), r = (int)(j & 65535), n = r >> 8, k = r & 255;
        v = ldin(Wg_h, ((long)l * 256 + k) * 256 + n, f);
    } else if (i < 262144) {              // Pgout
        const long j = i - 229376;
        const int n = (int)(j >> 8), k = (int)(j & 255);
        v = (n < 100) ? ldin(Wg_out, (long)k * 100 + n, f) : 0.f;
    } else if (i < 294912) {              // Pv0
        const long j = i - 262144;
        const int n = (int)(j >> 7), k = (int)(j & 127);
        v = (k < 101) ? ldin(Wv_in, (long)k * 256 + n, f) : 0.f;
    } else {                              // Pvh
        const long j = i - 294912;
        const int l = (int)(j >> 16), r = (int)(j & 65535), n = r >> 8, k = r & 255;
        v = ldin(Wv_h, ((long)l * 256 + k) * 256 + n, f);
    }
    P[i] = (h16)v;
}

// ---------------- fp32 GEMM (only for D = dW @ V^T) ----------------
template <bool A_RAW>
__global__ __launch_bounds__(256)
void gemm_kernel(const void* A, long aOff, int K,
                 const float* __restrict__ Bw, int N,
                 float* __restrict__ Cout, const int* __restrict__ dflag)
{
    const int f = *dflag;
    __shared__ float As[8][128];
    __shared__ float Bs[8][128];
    const int tid = threadIdx.x;
    const int tx = tid & 15, ty = tid >> 4;
    const long rowBase = (long)blockIdx.x * 128;
    const int colBase = blockIdx.y * 128;

    float acc[8][8];
#pragma unroll
    for (int i = 0; i < 8; i++)
#pragma unroll
        for (int j = 0; j < 8; j++) acc[i][j] = 0.f;

    for (int k0 = 0; k0 < K; k0 += 8) {
        {
            const int l = tid * 4;
            const int row = l >> 3;
            const int col = l & 7;
            const long abase = aOff + (rowBase + row) * (long)K + (k0 + col);
#pragma unroll
            for (int q = 0; q < 4; q++)
                As[col + q][row] = (k0 + col + q < K) ? ldin(A, abase + q, f) : 0.f;
        }
#pragma unroll
        for (int q = 0; q < 4; q++) {
            const int l = tid + 256 * q;
            const int kk = l >> 7, col = l & 127;
            const int gk = k0 + kk, gc = colBase + col;
            Bs[kk][col] = (gk < K && gc < N) ? Bw[(long)gk * N + gc] : 0.f;
        }
        __syncthreads();
#pragma unroll
        for (int kk = 0; kk < 8; kk++) {
            float a[8], b[8];
            const float4 a0 = *(const float4*)&As[kk][ty * 8];
            const float4 a1 = *(const float4*)&As[kk][ty * 8 + 4];
            const float4 b0 = *(const float4*)&Bs[kk][tx * 8];
            const float4 b1 = *(const float4*)&Bs[kk][tx * 8 + 4];
            a[0]=a0.x;a[1]=a0.y;a[2]=a0.z;a[3]=a0.w;a[4]=a1.x;a[5]=a1.y;a[6]=a1.z;a[7]=a1.w;
            b[0]=b0.x;b[1]=b0.y;b[2]=b0.z;b[3]=b0.w;b[4]=b1.x;b[5]=b1.y;b[6]=b1.z;b[7]=b1.w;
#pragma unroll
            for (int i = 0; i < 8; i++)
#pragma unroll
                for (int j = 0; j < 8; j++)
                    acc[i][j] += a[i] * b[j];
        }
        __syncthreads();
    }

#pragma unroll
    for (int i = 0; i < 8; i++) {
        const long row = rowBase + ty * 8 + i;
        const int colb = colBase + tx * 8;
        if (colb + 7 < N) {
            float4* cp = (float4*)(Cout + row * (long)N + colb);
            cp[0] = make_float4(acc[i][0], acc[i][1], acc[i][2], acc[i][3]);
            cp[1] = make_float4(acc[i][4], acc[i][5], acc[i][6], acc[i][7]);
        } else {
#pragma unroll
            for (int j = 0; j < 8; j++)
                if (colb + j < N) Cout[row * (long)N + colb + j] = acc[i][j];
        }
    }
}

// ---------------- chunked S scan: emits fp16 S (padded 104), vol in-place over D --
// vol = s*D*sqrt(h)  (includes sqrt(h)); S_new = s*(1+r*h) + vol.
__global__ __launch_bounds__(256)
void scan_chunk_kernel(float* __restrict__ S_carry, float* __restrict__ D,
                       const void* tgp, h16* __restrict__ Sh,
                       int t0, int Cg, void* outBase, h16* __restrict__ Shf,
                       int writeSf, const int* __restrict__ dflag)
{
    const int f = *dflag;
    const long idx = (long)blockIdx.x * blockDim.x + threadIdx.x;
    if (idx >= (long)NPATH * DIMN) return;
    const long b = idx / DIMN;
    const int d = (int)(idx - b * DIMN);
    float s = S_carry[idx];
    for (int lt = 0; lt < Cg; lt++) {
        const int t = t0 + lt;
        const float h = ldin(tgp, t + 1, f) - ldin(tgp, t, f);
        const long off = (long)lt * (NPATH * DIMN) + idx;
        const float vol = s * D[off] * sqrtf(h);
        const long shr = ((long)lt * NPATH + b) * 104;
        Sh[shr + d] = (h16)s;
        if (d < 4) Sh[shr + 100 + d] = (h16)0.f;
        D[off] = vol;
        s = s + RRATE * s * h + vol;
    }
    S_carry[idx] = s;
    if (writeSf) {
        if (f) ((float*)outBase)[NPATH + idx] = s;
        else   ((bf16*)outBase)[NPATH + idx] = __float2bfloat16(s);
        Shf[b * 104 + d] = (h16)s;
        if (d < 4) Shf[b * 104 + 100 + d] = (h16)0.f;
    }
}

// ---------------- fused MFMA fp16 MLP: 64 rows/block, 4 waves split N ----------
// GNET: 5 layers (last N=100 pad 128) + stoch epilogue (dot with vol, fp32).
// VNET: 4 layers + 256->1 dot epilogue. Weights pre-packed W^T[n][k] fp16.
// mfma_f32_16x16x32_f16: A[m=lane&15][k=quad*8+j]; B[k=quad*8+j][n=lane&15];
// C: col=lane&15, row=quad*4+reg.
template <bool GNET>
__global__ __launch_bounds__(256)
void mlp16_kernel(const h16* __restrict__ Sh, const float* __restrict__ vol,
                  const h16* __restrict__ P0, const h16* __restrict__ Ph,
                  const h16* __restrict__ Pout,
                  const void* b_in, const void* b_h, const void* b_out,
                  const void* wv_out, const void* tgp, int t0,
                  float* __restrict__ outv, const int* __restrict__ dflag)
{
    const int f = *dflag;
    __shared__ __align__(16) h16 Hs[64][264];     // 33,792 B (stride 264: 2-way-free b128)
    __shared__ __align__(16) h16 Wl[2][256][40];  // 40,960 B (stride 40: conflict-free b128)
    __shared__ float Ps[64][4];
    __shared__ float wvs[256];

    const int tid = threadIdx.x;
    const int w = tid >> 6, lane = tid & 63, quad = lane >> 4, m = lane & 15;
    const long row0 = (long)blockIdx.x * 64;
    const int t = t0 + (int)(row0 >> 13);         // 64 | 8192

    if (!GNET) wvs[tid] = ldin(wv_out, tid, f);

    // ---- stage layer-0 input x=[t,S]: Hs[r][0]=t, [1..100]=S, [101..127]=0 ----
    {
        const int r = tid >> 2, j = tid & 3;
        const h16* src = Sh + (row0 + r) * 104;
        for (int c = j; c < 13; c += 4) {
            const h16x8 v = *(const h16x8*)(src + c * 8);
#pragma unroll
            for (int q = 0; q < 8; q++) {
                const int d = c * 8 + q;
                if (d < 100) Hs[r][1 + d] = v[q];
            }
        }
        if (j == 0) Hs[r][0] = (h16)ldin(tgp, t, f);
        if (j == 1) {
            for (int k = 101; k < 128; k++) Hs[r][k] = (h16)0.f;
        }
    }

    const int NL = GNET ? 5 : 4;
    f32x4 acc[4][4];

    for (int l = 0; l < NL; l++) {
        const int Kp  = (l == 0) ? 128 : 256;
        const int N   = (l == 4) ? 128 : 256;
        const int NTW = (l == 4) ? 2 : 4;         // ntiles per wave
        const int nb16 = w * (NTW * 16);
        const h16* P = (l == 0) ? P0 : ((l < 4) ? (Ph + (long)(l - 1) * 65536) : Pout);

#pragma unroll
        for (int mt = 0; mt < 4; mt++)
#pragma unroll
            for (int nt = 0; nt < 4; nt++)
                acc[mt][nt] = (f32x4){0.f, 0.f, 0.f, 0.f};

        const int nkt = Kp >> 5;
        {   // stage k-chunk 0
            const int n0 = tid >> 2, j = tid & 3;
            for (int pg = 0; pg < (N >> 6); pg++) {
                const int n = n0 + pg * 64;
                *(h16x8*)&Wl[0][n][j * 8] = *(const h16x8*)(P + (long)n * Kp + j * 8);
            }
        }
        __syncthreads();

        for (int kt = 0; kt < nkt; kt++) {
            const int buf = kt & 1;
            if (kt + 1 < nkt) {   // prefetch next k-chunk into other buffer
                const int k0n = (kt + 1) << 5;
                const int n0 = tid >> 2, j = tid & 3;
                for (int pg = 0; pg < (N >> 6); pg++) {
                    const int n = n0 + pg * 64;
                    *(h16x8*)&Wl[buf ^ 1][n][j * 8] =
                        *(const h16x8*)(P + (long)n * Kp + k0n + j * 8);
                }
            }
            const int k0 = kt << 5;
            h16x8 a[4], b[4];
#pragma unroll
            for (int mt = 0; mt < 4; mt++)
                a[mt] = *(const h16x8*)&Hs[mt * 16 + m][k0 + quad * 8];
#pragma unroll
            for (int nt = 0; nt < 4; nt++)
                if (nt < NTW)
                    b[nt] = *(const h16x8*)&Wl[buf][nb16 + nt * 16 + m][quad * 8];
#pragma unroll
            for (int mt = 0; mt < 4; mt++)
#pragma unroll
                for (int nt = 0; nt < 4; nt++)
                    if (nt < NTW)
                        acc[mt][nt] = __builtin_amdgcn_mfma_f32_16x16x32_f16(
                            a[mt], b[nt], acc[mt][nt], 0, 0, 0);
            __syncthreads();
        }

        if (l < 4) {   // bias + ReLU + write back to Hs (wave owns cols nb16..nb16+63)
            const void* bp = (l == 0) ? b_in : b_h;
            const long bo = (l == 0) ? 0 : (long)(l - 1) * 256;
#pragma unroll
            for (int nt = 0; nt < 4; nt++) {
                const int col = nb16 + nt * 16 + m;
                const float bb = ldin(bp, bo + col, f);
#pragma unroll
                for (int mt = 0; mt < 4; mt++)
#pragma unroll
                    for (int i = 0; i < 4; i++) {
                        const float x = acc[mt][nt][i] + bb;
                        Hs[mt * 16 + quad * 4 + i][col] = (h16)fmaxf(x, 0.f);
                    }
            }
            __syncthreads();
        }
    }

    if (GNET) {
        // stoch = sum_col grad*vol  (vol already has sqrt(h))
        float p[4][4];
#pragma unroll
        for (int mt = 0; mt < 4; mt++)
#pragma unroll
            for (int i = 0; i < 4; i++) p[mt][i] = 0.f;
#pragma unroll
        for (int nt = 0; nt < 2; nt++) {
            const int col = w * 32 + nt * 16 + m;
            if (col < DIMN) {
                const float bo = ldin(b_out, col, f);
#pragma unroll
                for (int mt = 0; mt < 4; mt++)
#pragma unroll
                    for (int i = 0; i < 4; i++) {
                        const long row = row0 + mt * 16 + quad * 4 + i;
                        p[mt][i] += (acc[mt][nt][i] + bo) * vol[row * DIMN + col];
                    }
            }
        }
#pragma unroll
        for (int mt = 0; mt < 4; mt++)
#pragma unroll
            for (int i = 0; i < 4; i++) {
                float v = p[mt][i];
                v += __shfl_xor(v, 1, 16);
                v += __shfl_xor(v, 2, 16);
                v += __shfl_xor(v, 4, 16);
                v += __shfl_xor(v, 8, 16);
                p[mt][i] = v;
            }
        if (m == 0) {
#pragma unroll
            for (int mt = 0; mt < 4; mt++)
#pragma unroll
                for (int i = 0; i < 4; i++)
                    Ps[mt * 16 + quad * 4 + i][w] = p[mt][i];
        }
        __syncthreads();
        if (tid < 64)
            outv[row0 + tid] = Ps[tid][0] + Ps[tid][1] + Ps[tid][2] + Ps[tid][3];
    } else {
        // v = Hs . w_out + b_out (256 -> 1), 4 threads per row
        const int r = tid & 63, part = tid >> 6;
        float s = 0.f;
#pragma unroll
        for (int c = 0; c < 8; c++) {
            const h16x8 hv = *(const h16x8*)&Hs[r][part * 64 + c * 8];
#pragma unroll
            for (int q = 0; q < 8; q++)
                s += (float)hv[q] * wvs[part * 64 + c * 8 + q];
        }
        Ps[r][part] = s;
        __syncthreads();
        if (tid < 64)
            outv[row0 + tid] = Ps[tid][0] + Ps[tid][1] + Ps[tid][2] + Ps[tid][3]
                               + ldin(b_out, 0, f);
    }
}

// ---------------- final: error accumulation + v_f ----------------
__global__ void final_kernel(const float* __restrict__ v_all, const float* __restrict__ stoch,
                             const void* tgp, void* out, const int* __restrict__ dflag)
{
    const int f = *dflag;
    const int b = blockIdx.x * blockDim.x + threadIdx.x;
    if (b >= NPATH) return;
    float err = 0.f;
    for (int i = 0; i < NT - 1; i++) {
        const float h = ldin(tgp, i + 1, f) - ldin(tgp, i, f);
        const float e = v_all[(i + 1) * NPATH + b] - v_all[i * NPATH + b] * (1.f + RRATE * h)
                        - stoch[i * NPATH + b];
        err += e * e;
    }
    const long eoff = (long)NPATH + (long)NPATH * DIMN;
    const float vf = v_all[(long)(NT - 1) * NPATH + b];
    if (f) {
        ((float*)out)[b] = vf;
        ((float*)out)[eoff + b] = err;
    } else {
        ((bf16*)out)[b] = __float2bfloat16(vf);
        ((bf16*)out)[eoff + b] = __float2bfloat16(err);
    }
}

static inline int imin(int a, int b) { return a < b ? a : b; }

extern "C" void kernel_launch(void* const* d_in, const int* in_sizes, int n_in,
                              void* d_out, int out_size, void* d_ws, size_t ws_size,
                              hipStream_t stream) {
    const void* S0    = d_in[0];
    const void* dW    = d_in[1];
    const void* tg    = d_in[2];
    const void* V     = d_in[3];
    const void* Wg_in = d_in[4];
    const void* bg_in = d_in[5];
    const void* Wg_h  = d_in[6];
    const void* bg_h  = d_in[7];
    const void* Wg_out= d_in[8];
    const void* bg_out= d_in[9];
    const void* Wv_in = d_in[10];
    const void* bv_in = d_in[11];
    const void* Wv_h  = d_in[12];
    const void* bv_h  = d_in[13];
    const void* Wv_out= d_in[14];
    const void* bv_out= d_in[15];

    const size_t SZ_SD  = (size_t)NPATH * DIMN * 4;    // 3.28 MB (f32 per timestep)
    const size_t SZ_SH  = (size_t)NPATH * 104 * 2;     // 1.70 MB (fp16 padded S)

    // ---- carve workspace ----
    char* p = (char*)d_ws;
    auto carve = [&](size_t bytes) -> char* {
        char* r = p;
        p += (bytes + 255) & ~(size_t)255;
        return r;
    };
    int*   dflag     = (int*)carve(256);
    float* S_carry   = (float*)carve(SZ_SD);
    float* Vt        = (float*)carve((size_t)DIMN * DIMN * 4);
    float* v_all     = (float*)carve((size_t)NT * NPATH * 4);
    float* stoch_all = (float*)carve((size_t)(NT - 1) * NPATH * 4);
    h16*   Shf       = (h16*)carve(SZ_SH);
    h16*   Pk        = (h16*)carve((size_t)491520 * 2);     // packed fp16 weights
    const size_t fixed = (size_t)(p - (char*)d_ws);

    // packed-weight sub-pointers
    h16* Pg0   = Pk;
    h16* Pgh   = Pk + 32768;
    h16* Pgout = Pk + 229376;
    h16* Pv0   = Pk + 262144;
    h16* Pvh   = Pk + 294912;

    // adaptive time-chunk: per-timestep = D/vol (f32) + Sh (fp16)
    const size_t perC = SZ_SD + SZ_SH;                       // 4.98 MB
    size_t avail = (ws_size > fixed + 65536) ? (ws_size - fixed - 65536) : 0;
    int C = (int)(avail / perC);
    if (C < 1) C = 1;
    if (C > NT - 1) C = NT - 1;
    float* D_chunk = (float*)carve((size_t)C * SZ_SD);       // vol written in-place
    h16*   Sh      = (h16*)carve((size_t)C * SZ_SH);

    // ---- prep ----
    probe_kernel<<<dim3(1), dim3(64), 0, stream>>>(tg, dflag);
    init_kernel<<<dim3((NPATH * DIMN + 255) / 256), dim3(256), 0, stream>>>(S0, S_carry, V, Vt, dflag);
    pack_kernel<<<dim3(1920), dim3(256), 0, stream>>>(Wg_in, Wg_h, Wg_out, Wv_in, Wv_h, Pk, dflag);

    // ---- chunk loop over timesteps t in [0, 49) ----
    for (int t0 = 0; t0 < NT - 1; t0 += C) {
        const int Cg = imin(C, NT - 1 - t0);
        const int rows = Cg * NPATH;

        // D = dW[t0..t0+Cg) @ V^T
        gemm_kernel<true><<<dim3(rows / 128, 1), 256, 0, stream>>>(
            dW, (long)t0 * NPATH * DIMN, DIMN, Vt, DIMN, D_chunk, dflag);

        // scan: Sh (fp16), vol in-place over D, advance S_carry; S_f + Shf on last chunk
        scan_chunk_kernel<<<dim3((NPATH * DIMN + 255) / 256), 256, 0, stream>>>(
            S_carry, D_chunk, tg, Sh, t0, Cg, d_out, Shf,
            (t0 + Cg == NT - 1) ? 1 : 0, dflag);

        // g-net (MFMA, fused stoch epilogue)
        mlp16_kernel<true><<<dim3(rows / 64), 256, 0, stream>>>(
            Sh, D_chunk, Pg0, Pgh, Pgout, bg_in, bg_h, bg_out,
            nullptr, tg, t0, stoch_all + (long)t0 * NPATH, dflag);

        // v-net (MFMA, fused output dot)
        mlp16_kernel<false><<<dim3(rows / 64), 256, 0, stream>>>(
            Sh, nullptr, Pv0, Pvh, nullptr, bv_in, bv_h, bv_out,
            Wv_out, tg, t0, v_all + (long)t0 * NPATH, dflag);
    }

    // ---- v at t = 49 from Shf ----
    mlp16_kernel<false><<<dim3(NPATH / 64), 256, 0, stream>>>(
        Shf, nullptr, Pv0, Pvh, nullptr, bv_in, bv_h, bv_out,
        Wv_out, tg, NT - 1, v_all + (long)(NT - 1) * NPATH, dflag);

    // ---- error + v_f ----
    final_kernel<<<dim3(NPATH / 256), 256, 0, stream>>>(v_all, stoch_all, tg, d_out, dflag);
}